// Round 10
// baseline (369.334 us; speedup 1.0000x reference)
//
#include <hip/hip_runtime.h>

// Spatially varying anisotropic 2D elastic wave sim, 384x384, 192 steps.
// Round 9: de-phasing test at CONSTANT aggregate redundancy.
//  - OWN=16, HALO=8, K=8, TS=32: 576 blocks x 256 thr, 2x2 pts/thread,
//    24 launches. Aggregate staging work per step identical to R8
//    (589,824 pts), but ~2.25 blocks/CU co-resident -> while one block
//    drains LDS / waits at its barrier, another computes (R8's missing
//    overlap; R3's test of this was confounded by +50% redundancy and
//    a VGPR cap).
//  - LDS row stride 35 v2f (70 dwords == 6 mod 32): wave bank load at the
//    b64 floor (stride 33 would be 2x the floor).
//  - Keeps R8 machinery: float4 packed coeffs/state, sig preload,
//    lgkm-only barrier, packed v2f update chain.

typedef float v2f __attribute__((ext_vector_type(2)));

#define NXg 384
#define NYg 384
#define NPT (NXg * NYg)
#define NFRAMES 48

#define OWN 16
#define HALO 8
#define TS 32
#define KSTEPS 8
#define NLAUNCH 24
#define SCOL 35

#define H_   1e-4
#define DT_  5e-9
#define RHO_ 1610.0

#define B11_LO 5e10f
#define B11_HI 2.5e11f
#define B22_LO 5e9f
#define B22_HI 5e10f
#define B12_LO 5e9f
#define B12_HI 5e10f
#define B16_LO 0.0f
#define B16_HI 6e10f
#define B26_LO 0.0f
#define B26_HI 2e10f
#define B66_LO 5e9f
#define B66_HI 3e10f

static __device__ __constant__ float kScale  = (float)(DT_ * DT_ / (H_ * H_) / RHO_);
static __device__ __constant__ float kSrcScl = (float)(DT_ * DT_ / RHO_);

__device__ __forceinline__ float clipf(float v, float lo, float hi) {
    return fminf(fmaxf(v, lo), hi);
}
__device__ __forceinline__ v2f vfma(v2f a, v2f b, v2f c) {
    return __builtin_elementwise_fma(a, b, c);
}
__device__ __forceinline__ v2f vbc(float s) { v2f r; r[0] = s; r[1] = s; return r; }
__device__ __forceinline__ v2f vswap(v2f a) { return __builtin_shufflevector(a, a, 1, 0); }

// barrier that only waits LDS (no vmcnt drain)
#define LDS_BARRIER() asm volatile("s_waitcnt lgkmcnt(0)\n\ts_barrier" ::: "memory")

// ws float layout:
// [0..4NPT):    C0 = float4{A11, A22, A12p66, A16}  (pre-scaled)
// [4NPT..8NPT): C1 = float4{A26, A66, GS, 0}
// [8NPT..12NPT):  state set0: float4{cur.x, cur.y, old.x, old.y}
// [12NPT..16NPT): state set1

__global__ __launch_bounds__(256)
void setup_kernel(const float* __restrict__ lc11, const float* __restrict__ lc12,
                  const float* __restrict__ lc16, const float* __restrict__ lc22,
                  const float* __restrict__ lc26, const float* __restrict__ lc66,
                  const float* __restrict__ gauss, float* __restrict__ ws) {
    int i = blockIdx.x * blockDim.x + threadIdx.x;
    if (i >= NPT) return;
    float C11 = clipf(expf(lc11[i]), B11_LO, B11_HI);
    float C12 = clipf(expf(lc12[i]), B12_LO, B12_HI);
    float C16 = clipf(expf(lc16[i]), B16_LO, B16_HI);
    float C22 = clipf(expf(lc22[i]), B22_LO, B22_HI);
    float C26 = clipf(expf(lc26[i]), B26_LO, B26_HI);
    float C66 = clipf(expf(lc66[i]), B66_LO, B66_HI);
    float s = kScale;
    float4* C0 = (float4*)ws;
    float4* C1 = (float4*)(ws + 4 * (size_t)NPT);
    C0[i] = make_float4(C11 * s, C22 * s, (C12 + C66) * s, C16 * s);
    C1[i] = make_float4(C26 * s, C66 * s, gauss[i] * kSrcScl, 0.0f);
    float4* s0 = (float4*)(ws + 8 * (size_t)NPT);
    s0[i] = make_float4(0.0f, 0.0f, 0.0f, 0.0f);
}

__global__ __launch_bounds__(256)
void fused_kernel(const float* __restrict__ ws, const float* __restrict__ sig,
                  const float4* __restrict__ inS, float4* __restrict__ outS,
                  float* __restrict__ out, int L) {
    __shared__ v2f sb[2][TS][SCOL];

    const int tid = threadIdx.x;
    const int tx = tid >> 4;          // 0..15 row group
    const int ty = tid & 15;          // 0..15 col group
    const int r0 = 2 * tx;
    const int c0 = 2 * ty;
    const int gx0 = blockIdx.y * OWN - HALO;
    const int gy0 = blockIdx.x * OWN - HALO;

    const float4* __restrict__ C0 = (const float4*)ws;
    const float4* __restrict__ C1 = (const float4*)(ws + 4 * (size_t)NPT);

    v2f cur[4], old_[4];
    v2f ca[4], cb[4];                   // {A11,A66}, {A66,A22}
    float a12p66[4], a16[4], a26[4], gs[4];
    int gidx[4];

#pragma unroll
    for (int i = 0; i < 2; ++i) {
#pragma unroll
        for (int j = 0; j < 2; ++j) {
            int p = i * 2 + j;
            int gx = gx0 + r0 + i;
            int gy = gy0 + c0 + j;
            bool d = (unsigned)gx < (unsigned)NXg && (unsigned)gy < (unsigned)NYg;
            int g = d ? gx * NYg + gy : 0;
            gidx[p] = g;
            float4 st = d ? inS[g] : make_float4(0, 0, 0, 0);
            v2f c; c[0] = st.x; c[1] = st.y;
            v2f o; o[0] = st.z; o[1] = st.w;
            cur[p] = c; old_[p] = o;
            // out-of-domain -> zero coeffs => point stays exactly 0
            float4 k0 = d ? C0[g] : make_float4(0, 0, 0, 0);
            float4 k1 = d ? C1[g] : make_float4(0, 0, 0, 0);
            v2f t; t[0] = k0.x; t[1] = k1.y; ca[p] = t;   // {A11, A66}
            v2f u; u[0] = k1.y; u[1] = k0.y; cb[p] = u;   // {A66, A22}
            a12p66[p] = k0.z; a16[p] = k0.w; a26[p] = k1.x; gs[p] = k1.z;
        }
    }

    // preload all step source values (no s_loads inside the loop)
    const int t0 = L * KSTEPS;
    float sigv[KSTEPS];
#pragma unroll
    for (int k = 0; k < KSTEPS; ++k) sigv[k] = sig[t0 + k];

    // clamped halo coords (trapezoid garbage-tolerance at staging rim)
    const int rm  = (r0 > 0) ? r0 - 1 : 0;
    const int rp2 = (r0 + 2 < TS) ? r0 + 2 : TS - 1;
    const int cm  = (c0 > 0) ? c0 - 1 : 0;
    const int cp2 = (c0 + 2 < TS) ? c0 + 2 : TS - 1;

    // owned region = staging [8,24)^2 -> tx,ty in [4,12)
    const bool owned = (tx >= 4) && (tx < 12) && (ty >= 4) && (ty < 12);

    // publish initial values into buffer 0 (2 contiguous v2f per row -> b128)
#pragma unroll
    for (int i = 0; i < 2; ++i)
#pragma unroll
        for (int j = 0; j < 2; ++j)
            sb[0][r0 + i][c0 + j] = cur[i * 2 + j];
    LDS_BARRIER();

    v2f c20; c20[0] = 2.0f; c20[1] = 0.0f;
    v2f c02; c02[0] = 0.0f; c02[1] = 2.0f;
    const v2f m2 = vbc(-2.0f);
    const v2f qt = vbc(0.25f);
    const v2f two = vbc(2.0f);

#pragma unroll 1
    for (int s = 1; s <= KSTEPS; ++s) {
        const v2f (*rb)[SCOL] = sb[(s - 1) & 1];
        v2f (*wb)[SCOL] = sb[s & 1];
        v2f vsig; vsig[0] = 0.0f; vsig[1] = sigv[s - 1];

        // assemble 4x4 v2f window: own 2x2 from regs + 12 halo reads
        v2f v[4][4];
        v[1][1] = cur[0]; v[1][2] = cur[1];
        v[2][1] = cur[2]; v[2][2] = cur[3];
        v[0][0] = rb[rm][cm];     v[0][1] = rb[rm][c0];
        v[0][2] = rb[rm][c0 + 1]; v[0][3] = rb[rm][cp2];
        v[3][0] = rb[rp2][cm];    v[3][1] = rb[rp2][c0];
        v[3][2] = rb[rp2][c0 + 1]; v[3][3] = rb[rp2][cp2];
        v[1][0] = rb[r0][cm];      v[1][3] = rb[r0][cp2];
        v[2][0] = rb[r0 + 1][cm];  v[2][3] = rb[r0 + 1][cp2];

        // horizontal differences shared across the 4 points' cross-derivs
        v2f dh[4][2];
#pragma unroll
        for (int r = 0; r < 4; ++r)
#pragma unroll
            for (int j = 0; j < 2; ++j)
                dh[r][j] = v[r][j + 2] - v[r][j];

#pragma unroll
        for (int i = 0; i < 2; ++i)
#pragma unroll
            for (int j = 0; j < 2; ++j) {
                int p = i * 2 + j;
                int pi = 1 + i, pj = 1 + j;
                v2f c = v[pi][pj];
                v2f sxx = vfma(m2, c, v[pi - 1][pj] + v[pi + 1][pj]);   // pk
                v2f syy = vfma(m2, c, v[pi][pj - 1] + v[pi][pj + 1]);   // pk
                v2f sxy = qt * (dh[pi + 1][j] - dh[pi - 1][j]);         // pk

                // t4 = {2*sxy.x + sxx.y, sxx.x}; t5 = {syy.y, 2*sxy.y + syy.x}
                v2f t4 = vfma(c20, vbc(sxy[0]), vswap(sxx));
                v2f t5 = vfma(c02, vbc(sxy[1]), vswap(syy));
                v2f Lv = ca[p] * sxx;
                Lv = vfma(cb[p], syy, Lv);
                Lv = vfma(vbc(a12p66[p]), vswap(sxy), Lv);
                Lv = vfma(vbc(a16[p]), t4, Lv);
                Lv = vfma(vbc(a26[p]), t5, Lv);
                Lv = vfma(vsig, vbc(gs[p]), Lv);     // {lux, sig*gs + luy}
                v2f n = vfma(two, c, Lv) - old_[p];
                old_[p] = c;
                cur[p] = n;
            }

        // frame output at global t = t0+s-1; t%4==3 <=> s%4==0 (s=4,8)
        // fire-and-forget: the step barrier does NOT drain vmcnt
        if ((s & 3) == 0 && owned) {
            int f = 2 * L + (s >> 2) - 1;
            float* oux = out + (size_t)f * NPT;
            float* ouy = out + (size_t)(NFRAMES + f) * NPT;
#pragma unroll
            for (int p = 0; p < 4; ++p) {
                oux[gidx[p]] = cur[p][0];
                ouy[gidx[p]] = cur[p][1];
            }
        }

        // publish new values; ONE lgkm-only barrier per step (double buffered)
#pragma unroll
        for (int i = 0; i < 2; ++i)
#pragma unroll
            for (int j = 0; j < 2; ++j)
                wb[r0 + i][c0 + j] = cur[i * 2 + j];
        LDS_BARRIER();
    }

    if (owned) {
#pragma unroll
        for (int p = 0; p < 4; ++p) {
            float4 st = make_float4(cur[p][0], cur[p][1], old_[p][0], old_[p][1]);
            outS[gidx[p]] = st;
        }
    }
}

extern "C" void kernel_launch(void* const* d_in, const int* in_sizes, int n_in,
                              void* d_out, int out_size, void* d_ws, size_t ws_size,
                              hipStream_t stream) {
    const float* lc11  = (const float*)d_in[0];
    const float* lc12  = (const float*)d_in[1];
    const float* lc16  = (const float*)d_in[2];
    const float* lc22  = (const float*)d_in[3];
    const float* lc26  = (const float*)d_in[4];
    const float* lc66  = (const float*)d_in[5];
    const float* gauss = (const float*)d_in[6];
    const float* sig   = (const float*)d_in[7];

    float* ws  = (float*)d_ws;
    float* out = (float*)d_out;

    setup_kernel<<<(NPT + 255) / 256, 256, 0, stream>>>(lc11, lc12, lc16, lc22,
                                                        lc26, lc66, gauss, ws);

    float4* set0 = (float4*)(ws + 8 * (size_t)NPT);
    float4* set1 = (float4*)(ws + 12 * (size_t)NPT);

    dim3 grid(NXg / OWN, NYg / OWN);  // 24x24 = 576 blocks -> ~2.25 per CU
    for (int L = 0; L < NLAUNCH; ++L) {
        float4* iS = (L & 1) ? set1 : set0;
        float4* oS = (L & 1) ? set0 : set1;
        fused_kernel<<<grid, 256, 0, stream>>>(ws, sig, iS, oS, out, L);
    }
}